// Round 3
// baseline (138.834 us; speedup 1.0000x reference)
//
#include <hip/hip_runtime.h>
#include <hip/hip_bf16.h>

#define NVOX 100000
#define CIN 32
#define COUT 32
#define KOFF 27

typedef __attribute__((ext_vector_type(8))) short short8;
typedef __attribute__((ext_vector_type(4))) float float4v;

// fp32 -> bf16 round-to-nearest-even (finite inputs)
__device__ __forceinline__ short f2bf(float x) {
    union { float f; unsigned u; } v; v.f = x;
    unsigned u = v.u;
    u += 0x7FFFu + ((u >> 16) & 1u);
    return (short)(u >> 16);
}

__global__ __launch_bounds__(512) void subm_conv_kernel(
    const float* __restrict__ feat,     // fp32 [N,32]
    const float* __restrict__ weight,   // fp32 [27,32,32]
    const float* __restrict__ bias,     // fp32 [32]
    const int* __restrict__ nbr_idx,    // int32 [N,27]
    const int* __restrict__ nbr_mask,   // bool -> int32 [N,27]
    float* __restrict__ out)            // fp32 [N,32]
{
    // B fragments for all 27 offsets x 2 cout-tiles, MFMA B-operand order:
    // wlds[(k*2+t)*64 + ln][j] = W[k][ci=(ln>>4)*8+j][co=t*16+(ln&15)]
    __shared__ short8 wlds[KOFF * 2 * 64];

    const int tid = threadIdx.x;

    for (int g = tid; g < KOFF * 2 * 64; g += 512) {
        int k   = g >> 7;
        int rem = g & 127;
        int t   = rem >> 6;
        int ln  = rem & 63;
        int co  = t * 16 + (ln & 15);
        int cib = (ln >> 4) * 8;
        const float* wp = weight + (k * CIN + cib) * COUT + co;
        short8 b;
#pragma unroll
        for (int j = 0; j < 8; ++j) b[j] = f2bf(wp[j * COUT]);
        wlds[g] = b;
    }
    __syncthreads();

    const int lane = tid & 63;
    const int wave = tid >> 6;
    const int m    = lane & 15;
    const int quad = lane >> 4;

    const int v0 = (blockIdx.x * 8 + wave) * 16;   // 16 voxels per wave
    int v = v0 + m;
    if (v > NVOX - 1) v = NVOX - 1;                // clamp loads; stores guarded
    const int base = v * KOFF;

    float4v acc0 = {0.f, 0.f, 0.f, 0.f};
    float4v acc1 = {0.f, 0.f, 0.f, 0.f};

    for (int k = 0; k < KOFF; ++k) {
        int ok = nbr_mask[base + k];
        unsigned long long any = __ballot(ok != 0);
        if (any == 0ull) continue;                 // whole 16-voxel tile masked here

        int nb = nbr_idx[base + k];
        const float4v* frow = (const float4v*)(feat + (size_t)nb * CIN + quad * 8);
        float4v f0 = frow[0];
        float4v f1 = frow[1];
        if (!ok) {
            f0 = float4v{0.f, 0.f, 0.f, 0.f};
            f1 = float4v{0.f, 0.f, 0.f, 0.f};
        }
        short8 a;
        a[0] = f2bf(f0.x); a[1] = f2bf(f0.y); a[2] = f2bf(f0.z); a[3] = f2bf(f0.w);
        a[4] = f2bf(f1.x); a[5] = f2bf(f1.y); a[6] = f2bf(f1.z); a[7] = f2bf(f1.w);

        short8 b0 = wlds[k * 128 + lane];
        short8 b1 = wlds[k * 128 + 64 + lane];
        acc0 = __builtin_amdgcn_mfma_f32_16x16x32_bf16(a, b0, acc0, 0, 0, 0);
        acc1 = __builtin_amdgcn_mfma_f32_16x16x32_bf16(a, b1, acc1, 0, 0, 0);
    }

    // C/D layout: col (cout) = lane&15, row (voxel within tile) = quad*4 + reg
    const float bs0 = bias[m];
    const float bs1 = bias[16 + m];
#pragma unroll
    for (int r = 0; r < 4; ++r) {
        int vv = v0 + quad * 4 + r;
        if (vv < NVOX) {
            out[(size_t)vv * COUT + m]      = acc0[r] + bs0;
            out[(size_t)vv * COUT + 16 + m] = acc1[r] + bs1;
        }
    }
}

extern "C" void kernel_launch(void* const* d_in, const int* in_sizes, int n_in,
                              void* d_out, int out_size, void* d_ws, size_t ws_size,
                              hipStream_t stream) {
    const float* feat = (const float*)d_in[0];
    const float* wgt  = (const float*)d_in[1];
    const float* bias = (const float*)d_in[2];
    const int*   nidx = (const int*)d_in[3];
    const int*   nmsk = (const int*)d_in[4];
    float*       out  = (float*)d_out;

    const int block = 512;                         // 8 waves * 16 voxels = 128 voxels/block
    const int grid  = (NVOX + 127) / 128;          // 782
    subm_conv_kernel<<<grid, block, 0, stream>>>(feat, wgt, bias, nidx, nmsk, out);
}

// Round 4
// 111.093 us; speedup vs baseline: 1.2497x; 1.2497x over previous
//
#include <hip/hip_runtime.h>
#include <hip/hip_bf16.h>

#define NVOX 100000
#define CIN 32
#define COUT 32
#define KOFF 27

typedef __attribute__((ext_vector_type(8))) short short8;
typedef __attribute__((ext_vector_type(4))) float float4v;
typedef __attribute__((ext_vector_type(4))) int   int4v;

// fp32 -> bf16 round-to-nearest-even (finite inputs)
__device__ __forceinline__ short f2bf(float x) {
    union { float f; unsigned u; } v; v.f = x;
    unsigned u = v.u;
    u += 0x7FFFu + ((u >> 16) & 1u);
    return (short)(u >> 16);
}

__global__ __launch_bounds__(512, 4) void subm_conv_kernel(
    const float* __restrict__ feat,     // fp32 [N,32]
    const float* __restrict__ weight,   // fp32 [27,32,32]
    const float* __restrict__ bias,     // fp32 [32]
    const int* __restrict__ nbr_idx,    // int32 [N,27]
    const int* __restrict__ nbr_mask,   // bool -> int32 [N,27]
    float* __restrict__ out)            // fp32 [N,32]
{
    // B fragments for all 27 offsets x 2 cout-tiles, MFMA B-operand order:
    // wlds[(k*2+t)*64 + ln][j] = W[k][ci=(ln>>4)*8+j][co=t*16+(ln&15)]
    __shared__ short8 wlds[KOFF * 2 * 64];

    const int tid = threadIdx.x;

    for (int g = tid; g < KOFF * 2 * 64; g += 512) {
        int k   = g >> 7;
        int rem = g & 127;
        int t   = rem >> 6;
        int ln  = rem & 63;
        int co  = t * 16 + (ln & 15);
        int cib = (ln >> 4) * 8;
        const float* wp = weight + (k * CIN + cib) * COUT + co;
        short8 b;
#pragma unroll
        for (int j = 0; j < 8; ++j) b[j] = f2bf(wp[j * COUT]);
        wlds[g] = b;
    }
    __syncthreads();

    const int lane = tid & 63;
    const int wave = tid >> 6;
    const int m    = lane & 15;
    const int quad = lane >> 4;

    const int v0 = (blockIdx.x * 8 + wave) * 16;   // 16 voxels per wave
    int v = v0 + m;
    if (v > NVOX - 1) v = NVOX - 1;                // clamp loads; stores guarded
    const int base = v * KOFF;

    // ---- metadata: all 27 idx + 27 masks issued up front, branchless ----
    int enc[KOFF];
#pragma unroll
    for (int k = 0; k < KOFF; ++k) enc[k] = nbr_idx[base + k];
    int mok[KOFF];
#pragma unroll
    for (int k = 0; k < KOFF; ++k) mok[k] = nbr_mask[base + k];
#pragma unroll
    for (int k = 0; k < KOFF; ++k) enc[k] = mok[k] ? enc[k] : -1;

    float4v acc0 = {0.f, 0.f, 0.f, 0.f};
    float4v acc1 = {0.f, 0.f, 0.f, 0.f};

    const int cioff = quad * 8;

    // ---- depth-4 rotating gather pipeline, fully unrolled ----
    float4v b0buf[4], b1buf[4];
#pragma unroll
    for (int k = 0; k < 4; ++k) {
        int row = enc[k] < 0 ? 0 : enc[k];
        const float4v* fr = (const float4v*)(feat + (size_t)row * CIN + cioff);
        b0buf[k] = fr[0];
        b1buf[k] = fr[1];
    }

#pragma unroll
    for (int k = 0; k < KOFF; ++k) {
        const int slot = k & 3;
        float4v f0 = b0buf[slot];
        float4v f1 = b1buf[slot];
        if (k + 4 < KOFF) {
            int row = enc[k + 4] < 0 ? 0 : enc[k + 4];
            const float4v* fr = (const float4v*)(feat + (size_t)row * CIN + cioff);
            b0buf[slot] = fr[0];
            b1buf[slot] = fr[1];
        }

        union { short8 s; int4v i; } a;
        a.s[0] = f2bf(f0.x); a.s[1] = f2bf(f0.y); a.s[2] = f2bf(f0.z); a.s[3] = f2bf(f0.w);
        a.s[4] = f2bf(f1.x); a.s[5] = f2bf(f1.y); a.s[6] = f2bf(f1.z); a.s[7] = f2bf(f1.w);
        int zmask = enc[k] >= 0 ? ~0 : 0;          // zero A-frag for masked lanes
        a.i &= int4v{zmask, zmask, zmask, zmask};

        short8 wb0 = wlds[k * 128 + lane];
        short8 wb1 = wlds[k * 128 + 64 + lane];
        acc0 = __builtin_amdgcn_mfma_f32_16x16x32_bf16(a.s, wb0, acc0, 0, 0, 0);
        acc1 = __builtin_amdgcn_mfma_f32_16x16x32_bf16(a.s, wb1, acc1, 0, 0, 0);
    }

    // C/D layout: col (cout) = lane&15, row (voxel within tile) = quad*4 + reg
    const float bs0 = bias[m];
    const float bs1 = bias[16 + m];
#pragma unroll
    for (int r = 0; r < 4; ++r) {
        int vv = v0 + quad * 4 + r;
        if (vv < NVOX) {
            out[(size_t)vv * COUT + m]      = acc0[r] + bs0;
            out[(size_t)vv * COUT + 16 + m] = acc1[r] + bs1;
        }
    }
}

extern "C" void kernel_launch(void* const* d_in, const int* in_sizes, int n_in,
                              void* d_out, int out_size, void* d_ws, size_t ws_size,
                              hipStream_t stream) {
    const float* feat = (const float*)d_in[0];
    const float* wgt  = (const float*)d_in[1];
    const float* bias = (const float*)d_in[2];
    const int*   nidx = (const int*)d_in[3];
    const int*   nmsk = (const int*)d_in[4];
    float*       out  = (float*)d_out;

    const int block = 512;                         // 8 waves * 16 voxels = 128 voxels/block
    const int grid  = (NVOX + 127) / 128;          // 782
    subm_conv_kernel<<<grid, block, 0, stream>>>(feat, wgt, bias, nidx, nmsk, out);
}

// Round 5
// 104.235 us; speedup vs baseline: 1.3319x; 1.0658x over previous
//
#include <hip/hip_runtime.h>
#include <hip/hip_bf16.h>

#define NVOX 100000
#define CIN 32
#define COUT 32
#define KOFF 27

typedef __attribute__((ext_vector_type(8))) short short8;
typedef __attribute__((ext_vector_type(4))) float float4v;
typedef __attribute__((ext_vector_type(4))) int   int4v;

// fp32 -> bf16 round-to-nearest-even (finite inputs)
__device__ __forceinline__ short f2bf(float x) {
    union { float f; unsigned u; } v; v.f = x;
    unsigned u = v.u;
    u += 0x7FFFu + ((u >> 16) & 1u);
    return (short)(u >> 16);
}

// ---- pre-pass A: features fp32 -> bf16, 4 floats/thread ----
__global__ __launch_bounds__(256) void feat_cvt_kernel(
    const float* __restrict__ feat, unsigned short* __restrict__ fbf)
{
    int i = (blockIdx.x * 256 + threadIdx.x) * 4;   // NVOX*CIN = 3.2e6, divisible by 4
    if (i >= NVOX * CIN) return;
    float4v f = *(const float4v*)(feat + i);
    short s[4] = { f2bf(f.x), f2bf(f.y), f2bf(f.z), f2bf(f.w) };
    *(ulonglong1*)(fbf + i) = *(ulonglong1*)s;
}

// ---- pre-pass B: weights fp32 -> bf16 in B-fragment order ----
// wfrag[k*128 + t*64 + ln][j] = W[k][ci=(ln>>4)*8+j][co=t*16+(ln&15)]
__global__ __launch_bounds__(256) void wgt_cvt_kernel(
    const float* __restrict__ weight, short8* __restrict__ wfrag)
{
    int g = blockIdx.x * 256 + threadIdx.x;
    if (g >= KOFF * 2 * 64) return;
    int k   = g >> 7;
    int rem = g & 127;
    int t   = rem >> 6;
    int ln  = rem & 63;
    int co  = t * 16 + (ln & 15);
    int cib = (ln >> 4) * 8;
    const float* wp = weight + (k * CIN + cib) * COUT + co;
    short8 b;
#pragma unroll
    for (int j = 0; j < 8; ++j) b[j] = f2bf(wp[j * COUT]);
    wfrag[g] = b;
}

__global__ __launch_bounds__(512, 4) void subm_conv_kernel(
    const unsigned short* __restrict__ fbf,   // bf16 features [N,32] (ws)
    const short8* __restrict__ wfrag,         // bf16 B-fragments (ws)
    const float* __restrict__ bias,           // fp32 [32]
    const int* __restrict__ nbr_idx,          // int32 [N,27]
    const int* __restrict__ nbr_mask,         // bool -> int32 [N,27]
    float* __restrict__ out)                  // fp32 [N,32]
{
    __shared__ short8 wlds[KOFF * 2 * 64];

    const int tid = threadIdx.x;
    for (int g = tid; g < KOFF * 2 * 64; g += 512) wlds[g] = wfrag[g];
    __syncthreads();

    const int lane = tid & 63;
    const int wave = tid >> 6;
    const int m    = lane & 15;
    const int quad = lane >> 4;

    const int v0 = (blockIdx.x * 8 + wave) * 16;   // 16 voxels per wave
    int v = v0 + m;
    if (v > NVOX - 1) v = NVOX - 1;                // clamp loads; stores guarded
    const int base = v * KOFF;

    // ---- metadata: all 27 idx + 27 masks issued up front, branchless ----
    int enc[KOFF];
#pragma unroll
    for (int k = 0; k < KOFF; ++k) enc[k] = nbr_idx[base + k];
    int mok[KOFF];
#pragma unroll
    for (int k = 0; k < KOFF; ++k) mok[k] = nbr_mask[base + k];
#pragma unroll
    for (int k = 0; k < KOFF; ++k) enc[k] = mok[k] ? enc[k] : -1;

    float4v acc0 = {0.f, 0.f, 0.f, 0.f};
    float4v acc1 = {0.f, 0.f, 0.f, 0.f};

    const int cioff = quad * 8;                    // A-frag: 8 bf16 = one 16B load

    // ---- depth-8 rotating gather pipeline, fully unrolled ----
    short8 abuf[8];
#pragma unroll
    for (int k = 0; k < 8; ++k) {
        int row = enc[k] < 0 ? 0 : enc[k];
        abuf[k] = *(const short8*)(fbf + (size_t)row * CIN + cioff);
    }

#pragma unroll
    for (int k = 0; k < KOFF; ++k) {
        const int slot = k & 7;
        union { short8 s; int4v i; } a;
        a.s = abuf[slot];
        if (k + 8 < KOFF) {
            int row = enc[k + 8] < 0 ? 0 : enc[k + 8];
            abuf[slot] = *(const short8*)(fbf + (size_t)row * CIN + cioff);
        }
        int zmask = enc[k] >= 0 ? ~0 : 0;          // zero A-frag for masked lanes
        a.i &= int4v{zmask, zmask, zmask, zmask};

        short8 wb0 = wlds[k * 128 + lane];
        short8 wb1 = wlds[k * 128 + 64 + lane];
        acc0 = __builtin_amdgcn_mfma_f32_16x16x32_bf16(a.s, wb0, acc0, 0, 0, 0);
        acc1 = __builtin_amdgcn_mfma_f32_16x16x32_bf16(a.s, wb1, acc1, 0, 0, 0);
    }

    // C/D layout: col (cout) = lane&15, row (voxel within tile) = quad*4 + reg
    const float bs0 = bias[m];
    const float bs1 = bias[16 + m];
#pragma unroll
    for (int r = 0; r < 4; ++r) {
        int vv = v0 + quad * 4 + r;
        if (vv < NVOX) {
            out[(size_t)vv * COUT + m]      = acc0[r] + bs0;
            out[(size_t)vv * COUT + 16 + m] = acc1[r] + bs1;
        }
    }
}

extern "C" void kernel_launch(void* const* d_in, const int* in_sizes, int n_in,
                              void* d_out, int out_size, void* d_ws, size_t ws_size,
                              hipStream_t stream) {
    const float* feat = (const float*)d_in[0];
    const float* wgt  = (const float*)d_in[1];
    const float* bias = (const float*)d_in[2];
    const int*   nidx = (const int*)d_in[3];
    const int*   nmsk = (const int*)d_in[4];
    float*       out  = (float*)d_out;

    unsigned short* fbf   = (unsigned short*)d_ws;                 // 6,400,000 B
    short8*         wfrag = (short8*)((char*)d_ws + (size_t)NVOX * CIN * 2);  // 55,296 B

    feat_cvt_kernel<<<(NVOX * CIN / 4 + 255) / 256, 256, 0, stream>>>(feat, fbf);
    wgt_cvt_kernel<<<(KOFF * 2 * 64 + 255) / 256, 256, 0, stream>>>(wgt, wfrag);

    const int block = 512;                         // 8 waves * 16 voxels = 128 voxels/block
    const int grid  = (NVOX + 127) / 128;          // 782
    subm_conv_kernel<<<grid, block, 0, stream>>>(fbf, wfrag, bias, nidx, nmsk, out);
}